// Round 3
// baseline (74.490 us; speedup 1.0000x reference)
//
#include <hip/hip_runtime.h>
#include <math.h>

// MCModel: reference output = (M^idx_T e_s)[IDX_Z] (per-step normalization
// cancels exactly). Free-space trinomial closed form (absorbing-boundary
// image correction ~e^-53 relative -> negligible):
//   out = sum_a  n!/(a! b! c!) p2^a pmid^b p1^c,  a-c = d = IDX_Z-idx_s,
//         b = n-a-c,  a in [max(d,0), (n+d)/2]   (~4873 fp64 terms)
//
// R2 post-mortem: timed path = 39.4us harness d_ws re-poison fill (fixed,
// uncontrollable) + ~7us harness machinery + ~15us for TWO kernel nodes
// dominated by lib fp64 lgamma (~5k cyc/call). R3: ONE graph node (single
// block, 1024 threads, LDS reduce) + hand-rolled Stirling lgamma
// (1 log + ~15 fp64 ops, abs err <3e-10 for x>=8; significant terms have
// a~2750,b~4750,c~2500 so deep in asymptotic regime; small-arg shift only
// touches e^-100 tails). ~1.5M fp64 ops on one CU ~= 5us.

#define IDX_Z_CONST 512
#define BTHREADS 1024

// Stirling-series lgamma, valid x >= 1 (abs err <3e-10 at x=8, <1e-16 by
// x~100). Args < 8 are shifted up via Gamma(x) recurrence (tail terms only).
__device__ inline double lgamma_stirling(double x) {
    double corr = 0.0;
    if (x < 8.0) {
        double p = 1.0;
        do { p *= x; x += 1.0; } while (x < 8.0);
        corr = -log(p);
    }
    const double ix  = 1.0 / x;
    const double ix2 = ix * ix;
    const double ser = ix * (8.3333333333333333333e-2      // 1/12
                 + ix2 * (-2.7777777777777777778e-3       // -1/360
                 + ix2 * ( 7.9365079365079365079e-4)));   //  1/1260
    return corr + (x - 0.5) * log(x) - x
         + 0.91893853320467274178032973640562 + ser;      // 0.5*ln(2*pi)
}

__global__ __launch_bounds__(BTHREADS)
void mc_trinomial_kernel(const float* __restrict__ mu,
                         const int* __restrict__ idx_T,
                         const int* __restrict__ idx_s,
                         float* __restrict__ out) {
    const int n = idx_T[0];
    const int s = idx_s[0];
    const int d = IDX_Z_CONST - s;

    // Reproduce the reference's fp32 coefficient computation exactly.
    const float DTf = 2e-06f;
    const float mu0 = mu[0];
    const float m1  = mu0 * DTf;
    const float m2  = m1 * m1 + DTf;          // SIGMA^2 = 1
    const float DXf = 2.0f / 1024.0f;         // 2^-9, exact in fp32
    const float DX2 = DXf * DXf;              // 2^-18, exact
    const float p1f = (m2 / DX2 + m1 / DXf) * 0.5f;
    const float p2f = (m2 / DX2 - m1 / DXf) * 0.5f;
    const float pmf = 1.0f - p1f - p2f;

    const double lp1 = log((double)p1f);
    const double lp2 = log((double)p2f);
    const double lpm = log((double)pmf);
    const double lgn = lgamma_stirling((double)n + 1.0);

    const int a_min = (d > 0) ? d : 0;
    const int a_max = ((n + d) >= 0) ? ((n + d) / 2) : -1;

    double local = 0.0;
    for (int a = a_min + (int)threadIdx.x; a <= a_max; a += BTHREADS) {
        const int c = a - d;          // down-moves (weight p1)
        const int b = n - a - c;      // stays      (weight pmid)
        const double L = lgn
                       - lgamma_stirling((double)a + 1.0)
                       - lgamma_stirling((double)b + 1.0)
                       - lgamma_stirling((double)c + 1.0)
                       + (double)a * lp2 + (double)b * lpm + (double)c * lp1;
        local += exp(L);              // tail underflow to 0 is harmless
    }

    // Block reduction: wave64 butterfly, then LDS across the 16 waves.
    #pragma unroll
    for (int off = 32; off > 0; off >>= 1)
        local += __shfl_down(local, off, 64);
    __shared__ double red[BTHREADS / 64];
    const int lane = threadIdx.x & 63;
    const int wave = threadIdx.x >> 6;
    if (lane == 0) red[wave] = local;
    __syncthreads();
    if (threadIdx.x == 0) {
        double sum = 0.0;
        #pragma unroll
        for (int i = 0; i < BTHREADS / 64; ++i) sum += red[i];
        out[0] = (float)sum;
    }
}

extern "C" void kernel_launch(void* const* d_in, const int* in_sizes, int n_in,
                              void* d_out, int out_size, void* d_ws, size_t ws_size,
                              hipStream_t stream) {
    const float* mu   = (const float*)d_in[0];
    const int*   idxT = (const int*)d_in[1];
    const int*   idxS = (const int*)d_in[2];
    float*       outp = (float*)d_out;
    hipLaunchKernelGGL(mc_trinomial_kernel, dim3(1), dim3(BTHREADS), 0, stream,
                       mu, idxT, idxS, outp);
}

// Round 4
// 61.090 us; speedup vs baseline: 1.2194x; 1.2194x over previous
//
#include <hip/hip_runtime.h>
#include <math.h>

// MCModel: reference output = (M^idx_T e_s)[IDX_Z] (per-step normalization
// cancels exactly). Free-space trinomial closed form (absorbing-boundary
// image correction ~e^-53 relative -> negligible):
//   out = sum_a  n!/(a! b! c!) p2^a pmid^b p1^c,  a-c = d = IDX_Z-idx_s,
//         b = n-a-c,  a in [max(d,0), (n+d)/2]   (~4873 fp64 terms)
//
// R3 post-mortem: single-block Stirling = 28us (CU starvation: 1 of 256 CUs
// busy, latency-bound on chained fp64 transcendentals). R2 showed 128-block
// spread is worth ~25us; graph node gap is only ~2us. R4 = both wins:
// 128 blocks x 64 threads, ONE term per thread (4873 terms <= 8192 threads),
// Stirling lgamma (1 log + 1 div + ~12 fma; abs err <3e-10 for x>=8,
// small-arg shift only touches e^-100 underflowing tails), deterministic
// per-block partials in d_ws (no atomics, no init), tiny finalize node.

#define IDX_Z_CONST 512
#define NBLOCKS 128
#define BTHREADS 64

// Stirling-series lgamma, abs err <3e-10 for x >= 8; args < 8 shifted up.
__device__ inline double lgamma_stirling(double x) {
    double corr = 0.0;
    if (x < 8.0) {
        double p = 1.0;
        do { p *= x; x += 1.0; } while (x < 8.0);
        corr = -log(p);
    }
    const double ix  = 1.0 / x;
    const double ix2 = ix * ix;
    const double ser = ix * (8.3333333333333333333e-2      // 1/12
                 + ix2 * (-2.7777777777777777778e-3       // -1/360
                 + ix2 * ( 7.9365079365079365079e-4)));   //  1/1260
    return corr + (x - 0.5) * log(x) - x
         + 0.91893853320467274178032973640562 + ser;      // 0.5*ln(2*pi)
}

__global__ __launch_bounds__(BTHREADS)
void mc_terms_kernel(const float* __restrict__ mu,
                     const int* __restrict__ idx_T,
                     const int* __restrict__ idx_s,
                     double* __restrict__ partials) {
    const int n = idx_T[0];
    const int s = idx_s[0];
    const int d = IDX_Z_CONST - s;

    // Reproduce the reference's fp32 coefficient computation exactly.
    const float DTf = 2e-06f;
    const float mu0 = mu[0];
    const float m1  = mu0 * DTf;
    const float m2  = m1 * m1 + DTf;          // SIGMA^2 = 1
    const float DXf = 2.0f / 1024.0f;         // 2^-9, exact in fp32
    const float DX2 = DXf * DXf;              // 2^-18, exact
    const float p1f = (m2 / DX2 + m1 / DXf) * 0.5f;
    const float p2f = (m2 / DX2 - m1 / DXf) * 0.5f;
    const float pmf = 1.0f - p1f - p2f;

    const double lp1 = log((double)p1f);
    const double lp2 = log((double)p2f);
    const double lpm = log((double)pmf);
    const double lgn = lgamma_stirling((double)n + 1.0);

    const int a_min = (d > 0) ? d : 0;
    const int a_max = ((n + d) >= 0) ? ((n + d) / 2) : -1;

    double local = 0.0;
    const int stride = NBLOCKS * BTHREADS;
    for (int a = a_min + (int)(blockIdx.x * BTHREADS + threadIdx.x);
         a <= a_max; a += stride) {           // exactly 0 or 1 iterations here
        const int c = a - d;          // down-moves (weight p1)
        const int b = n - a - c;      // stays      (weight pmid)
        const double L = lgn
                       - lgamma_stirling((double)a + 1.0)
                       - lgamma_stirling((double)b + 1.0)
                       - lgamma_stirling((double)c + 1.0)
                       + (double)a * lp2 + (double)b * lpm + (double)c * lp1;
        local += exp(L);              // tail underflow to 0 is harmless
    }

    // Block = one wave: butterfly reduce, lane 0 writes the partial.
    #pragma unroll
    for (int off = 32; off > 0; off >>= 1)
        local += __shfl_down(local, off, 64);
    if (threadIdx.x == 0) partials[blockIdx.x] = local;
}

__global__ __launch_bounds__(NBLOCKS)
void mc_finalize_kernel(const double* __restrict__ partials,
                        float* __restrict__ out) {
    double v = partials[threadIdx.x];      // NBLOCKS=128 threads, 2 waves
    #pragma unroll
    for (int off = 32; off > 0; off >>= 1)
        v += __shfl_down(v, off, 64);
    __shared__ double red[2];
    if ((threadIdx.x & 63) == 0) red[threadIdx.x >> 6] = v;
    __syncthreads();
    if (threadIdx.x == 0) out[0] = (float)(red[0] + red[1]);
}

extern "C" void kernel_launch(void* const* d_in, const int* in_sizes, int n_in,
                              void* d_out, int out_size, void* d_ws, size_t ws_size,
                              hipStream_t stream) {
    const float* mu   = (const float*)d_in[0];
    const int*   idxT = (const int*)d_in[1];
    const int*   idxS = (const int*)d_in[2];
    float*       outp = (float*)d_out;
    double*      part = (double*)d_ws;

    hipLaunchKernelGGL(mc_terms_kernel, dim3(NBLOCKS), dim3(BTHREADS), 0, stream,
                       mu, idxT, idxS, part);
    hipLaunchKernelGGL(mc_finalize_kernel, dim3(1), dim3(NBLOCKS), 0, stream,
                       part, outp);
}